// Round 7
// baseline (292.096 us; speedup 1.0000x reference)
//
#include <hip/hip_runtime.h>
#include <stdint.h>

#define C_CH 128

typedef float floatx2 __attribute__((ext_vector_type(2)));
typedef float floatx4 __attribute__((ext_vector_type(4)));

// ---------------- fallback (atomic) helpers ----------------
__device__ __forceinline__ unsigned fkey(float x) {
  unsigned b = __float_as_uint(x);
  return b ^ ((unsigned)((int)b >> 31) | 0x80000000u);
}
__device__ __forceinline__ float fdec(unsigned k) {
  unsigned b = (k & 0x80000000u) ? (k & 0x7FFFFFFFu) : ~k;
  return __uint_as_float(b);
}

__global__ __launch_bounds__(256) void pool_atomic(
    const float4* __restrict__ in4, const int* __restrict__ vt_replace,
    const int* __restrict__ vt_map, unsigned* __restrict__ outk, int64_t n4) {
  const int64_t stride = (int64_t)gridDim.x * blockDim.x;
  for (int64_t t = (int64_t)blockIdx.x * blockDim.x + threadIdx.x; t < n4;
       t += stride) {
    const int row = (int)(t >> 5);
    const int c4  = (int)(t & 31);
    int s = 0;
    if ((threadIdx.x & 31) == 0) s = vt_map[vt_replace[row]];
    s = __shfl(s, 0, 32);
    const float4 v = in4[t];
    unsigned* o = outk + ((int64_t)s << 7) + (c4 << 2);
    atomicMax(o + 0, fkey(v.x));
    atomicMax(o + 1, fkey(v.y));
    atomicMax(o + 2, fkey(v.z));
    atomicMax(o + 3, fkey(v.w));
  }
}
__global__ __launch_bounds__(256) void decode_k(unsigned* __restrict__ io, int64_t n4) {
  const int64_t stride = (int64_t)gridDim.x * blockDim.x;
  for (int64_t t = (int64_t)blockIdx.x * blockDim.x + threadIdx.x; t < n4;
       t += stride) {
    uint4* p = ((uint4*)io) + t;
    uint4 k = *p;
    float4 f;
    f.x = k.x ? fdec(k.x) : 0.0f;
    f.y = k.y ? fdec(k.y) : 0.0f;
    f.z = k.z ? fdec(k.z) : 0.0f;
    f.w = k.w ? fdec(k.w) : 0.0f;
    *(float4*)p = f;
  }
}

// ---------------- CSR path ----------------

__global__ __launch_bounds__(256) void zero_u32(unsigned* __restrict__ p, int m) {
  const int stride = gridDim.x * blockDim.x;
  for (int i = blockIdx.x * blockDim.x + threadIdx.x; i < m; i += stride)
    p[i] = 0u;
}

// Pass A: histogram of seg = vt_map[vt_replace[i]].
__global__ __launch_bounds__(256) void seg_hist(
    const int* __restrict__ vt_replace, const int* __restrict__ vt_map,
    unsigned* __restrict__ counts, int n) {
  const int stride = gridDim.x * blockDim.x;
  for (int i = blockIdx.x * blockDim.x + threadIdx.x; i < n; i += stride) {
    const int s = vt_map[vt_replace[i]];
    atomicAdd(&counts[s], 1u);
  }
}

// Pass B: allocate disjoint CSR ranges (segment order irrelevant for max).
// Wave-scan + one atomicAdd(total) per wave replaces the 3-kernel scan.
__global__ __launch_bounds__(256) void alloc_offsets(
    const unsigned* __restrict__ counts, unsigned* __restrict__ cursor,
    unsigned* __restrict__ total, int m) {
  const int i = blockIdx.x * blockDim.x + threadIdx.x;
  const int lane = threadIdx.x & 63;
  const unsigned c = (i < m) ? counts[i] : 0u;
  unsigned x = c;                       // inclusive wave scan
  for (int d = 1; d < 64; d <<= 1) {
    const unsigned t = __shfl_up(x, d, 64);
    if (lane >= d) x += t;
  }
  const unsigned excl = x - c;
  const unsigned tot  = __shfl(x, 63, 64);
  unsigned base = 0;
  if (lane == 63) base = atomicAdd(total, tot);
  base = __shfl(base, 63, 64);
  if (i < m) cursor[i] = base + excl;
}

// Pass C: scatter packed (rowid, seg) pairs into CSR buckets.
__global__ __launch_bounds__(256) void scatter_rows2(
    const int* __restrict__ vt_replace, const int* __restrict__ vt_map,
    unsigned* __restrict__ cursor, int2* __restrict__ rowseg, int n) {
  const int stride = gridDim.x * blockDim.x;
  for (int i = blockIdx.x * blockDim.x + threadIdx.x; i < n; i += stride) {
    const int s = vt_map[vt_replace[i]];
    const unsigned p = atomicAdd(&cursor[s], 1u);
    rowseg[p] = make_int2(i, s);
  }
}

// Pass D: empty segments -> zeros (CSR walk never visits them).
__global__ __launch_bounds__(256) void fill_empty(
    const unsigned* __restrict__ counts, floatx4* __restrict__ out4, int m) {
  const int total = m * 32;
  const int stride = gridDim.x * blockDim.x;
  for (int t = blockIdx.x * blockDim.x + threadIdx.x; t < total; t += stride) {
    const int s = t >> 5;
    if (counts[s] == 0u) out4[t] = (floatx4)(0.0f);
  }
}

// Pass E: chunked-ownership gather. One wave64 per 64 CSR positions; a wave
// owns every run STARTING in its window (finishes tails past the edge).
// Row = 64 lanes x float2 = one 512B load instruction. All run-boundary
// branches are wave-uniform (start mask in an SGPR via ballot).
__global__ __launch_bounds__(256) void gather_chunk(
    const floatx2* __restrict__ in2, const int2* __restrict__ rowseg,
    floatx2* __restrict__ out2, int n) {
  const int wv = blockIdx.x * 4 + (threadIdx.x >> 6);
  const int P0 = wv << 6;
  if (P0 >= n) return;
  const int lane = threadIdx.x & 63;
  const int P1 = min(P0 + 64, n);

  const int pos = P0 + lane;
  int rid_w = 0, seg_w = -1;
  if (pos < n) { const int2 rs = rowseg[pos]; rid_w = rs.x; seg_w = rs.y; }

  int segprev = -1;
  if (P0 > 0) segprev = rowseg[P0 - 1].y;        // uniform broadcast load

  int sprev = __shfl_up(seg_w, 1, 64);
  if (lane == 0) sprev = segprev;
  const bool startf = (pos < n) && (seg_w != sprev);
  const unsigned long long M = __ballot(startf);
  if (M == 0ULL) return;                          // window interior to a run

  int p = P0 + (int)__builtin_ctzll(M);
  floatx2 acc = (floatx2)(-INFINITY);

  // fast path: 4 rows in flight, all in-window, no exit possible
  while (p + 4 < P1) {
    const int i0 = p - P0;
    const int r0 = __shfl(rid_w, i0 + 0, 64);
    const int r1 = __shfl(rid_w, i0 + 1, 64);
    const int r2 = __shfl(rid_w, i0 + 2, 64);
    const int r3 = __shfl(rid_w, i0 + 3, 64);
    const floatx2 v0 = __builtin_nontemporal_load(&in2[(int64_t)r0 * 64 + lane]);
    const floatx2 v1 = __builtin_nontemporal_load(&in2[(int64_t)r1 * 64 + lane]);
    const floatx2 v2 = __builtin_nontemporal_load(&in2[(int64_t)r2 * 64 + lane]);
    const floatx2 v3 = __builtin_nontemporal_load(&in2[(int64_t)r3 * 64 + lane]);

    acc.x = fmaxf(acc.x, v0.x); acc.y = fmaxf(acc.y, v0.y);
    if ((M >> (i0 + 1)) & 1) {
      const int sg = __shfl(seg_w, i0 + 0, 64);
      __builtin_nontemporal_store(acc, &out2[(int64_t)sg * 64 + lane]);
      acc = (floatx2)(-INFINITY);
    }
    acc.x = fmaxf(acc.x, v1.x); acc.y = fmaxf(acc.y, v1.y);
    if ((M >> (i0 + 2)) & 1) {
      const int sg = __shfl(seg_w, i0 + 1, 64);
      __builtin_nontemporal_store(acc, &out2[(int64_t)sg * 64 + lane]);
      acc = (floatx2)(-INFINITY);
    }
    acc.x = fmaxf(acc.x, v2.x); acc.y = fmaxf(acc.y, v2.y);
    if ((M >> (i0 + 3)) & 1) {
      const int sg = __shfl(seg_w, i0 + 2, 64);
      __builtin_nontemporal_store(acc, &out2[(int64_t)sg * 64 + lane]);
      acc = (floatx2)(-INFINITY);
    }
    acc.x = fmaxf(acc.x, v3.x); acc.y = fmaxf(acc.y, v3.y);
    if ((M >> (i0 + 4)) & 1) {
      const int sg = __shfl(seg_w, i0 + 3, 64);
      __builtin_nontemporal_store(acc, &out2[(int64_t)sg * 64 + lane]);
      acc = (floatx2)(-INFINITY);
    }
    p += 4;
  }

  // serial tail: window edge + run tail past P1
  while (true) {
    int rid, sg;
    if (p < P1) {
      rid = __shfl(rid_w, p - P0, 64);
      sg  = __shfl(seg_w, p - P0, 64);
    } else {
      const int2 t = rowseg[p];                  // uniform broadcast load
      rid = t.x; sg = t.y;
    }
    const floatx2 v = __builtin_nontemporal_load(&in2[(int64_t)rid * 64 + lane]);
    acc.x = fmaxf(acc.x, v.x); acc.y = fmaxf(acc.y, v.y);

    bool end;
    if (p + 1 >= n)      end = true;
    else if (p + 1 < P1) end = (M >> (p + 1 - P0)) & 1;
    else                 end = (rowseg[p + 1].y != sg);

    if (end) {
      __builtin_nontemporal_store(acc, &out2[(int64_t)sg * 64 + lane]);
      acc = (floatx2)(-INFINITY);
      if (p + 1 >= P1) break;                    // next run owned by next wave
    }
    ++p;
  }
}

// ---------------- launch ----------------
extern "C" void kernel_launch(void* const* d_in, const int* in_sizes, int n_in_args,
                              void* d_out, int out_size, void* d_ws, size_t ws_size,
                              hipStream_t stream) {
  (void)n_in_args;
  const float*  in         = (const float*)d_in[0];
  const int*    vt_replace = (const int*)d_in[1];
  const int*    vt_map     = (const int*)d_in[2];
  const int     n_in = in_sizes[1];
  const int     m    = out_size / C_CH;          // N_OUT

  // workspace carve (256B aligned)
  uintptr_t p = (uintptr_t)d_ws;
  auto carve = [&](size_t bytes) {
    uintptr_t r = p;
    p += (bytes + 255) & ~(size_t)255;
    return (void*)r;
  };
  int2*     rowseg = (int2*)carve((size_t)n_in * 8);
  unsigned* counts = (unsigned*)carve(((size_t)m + 1) * 4);  // counts[m] = total
  unsigned* cursor = (unsigned*)carve((size_t)m * 4);
  unsigned* total  = counts + m;                             // zeroed with counts
  const size_t needed = p - (uintptr_t)d_ws;

  if (ws_size < needed) {
    unsigned* outk = (unsigned*)d_out;
    (void)hipMemsetAsync(d_out, 0, (size_t)out_size * sizeof(float), stream);
    const int64_t n4 = (int64_t)n_in * (C_CH / 4);
    pool_atomic<<<2048, 256, 0, stream>>>((const float4*)in, vt_replace, vt_map, outk, n4);
    decode_k<<<2048, 256, 0, stream>>>(outk, (int64_t)out_size / 4);
    return;
  }

  // zero counts AND total (adjacent) every call — total must restart at 0
  // each replay or cursor offsets run away (graph replays reuse d_ws).
  zero_u32<<<256, 256, 0, stream>>>(counts, m + 1);

  seg_hist<<<2048, 256, 0, stream>>>(vt_replace, vt_map, counts, n_in);

  alloc_offsets<<<(m + 255) / 256, 256, 0, stream>>>(counts, cursor, total, m);

  scatter_rows2<<<2048, 256, 0, stream>>>(vt_replace, vt_map, cursor, rowseg, n_in);

  fill_empty<<<2048, 256, 0, stream>>>(counts, (floatx4*)d_out, m);

  const int waves = (n_in + 63) / 64;
  gather_chunk<<<(waves + 3) / 4, 256, 0, stream>>>((const floatx2*)in, rowseg,
                                                    (floatx2*)d_out, n_in);
}

// Round 8
// 260.901 us; speedup vs baseline: 1.1196x; 1.1196x over previous
//
#include <hip/hip_runtime.h>
#include <stdint.h>

#define C_CH 128

typedef float floatx4 __attribute__((ext_vector_type(4)));

// ---------------- fallback (atomic) helpers ----------------
__device__ __forceinline__ unsigned fkey(float x) {
  unsigned b = __float_as_uint(x);
  return b ^ ((unsigned)((int)b >> 31) | 0x80000000u);
}
__device__ __forceinline__ float fdec(unsigned k) {
  unsigned b = (k & 0x80000000u) ? (k & 0x7FFFFFFFu) : ~k;
  return __uint_as_float(b);
}

__global__ __launch_bounds__(256) void pool_atomic(
    const float4* __restrict__ in4, const int* __restrict__ vt_replace,
    const int* __restrict__ vt_map, unsigned* __restrict__ outk, int64_t n4) {
  const int64_t stride = (int64_t)gridDim.x * blockDim.x;
  for (int64_t t = (int64_t)blockIdx.x * blockDim.x + threadIdx.x; t < n4;
       t += stride) {
    const int row = (int)(t >> 5);
    const int c4  = (int)(t & 31);
    int s = 0;
    if ((threadIdx.x & 31) == 0) s = vt_map[vt_replace[row]];
    s = __shfl(s, 0, 32);
    const float4 v = in4[t];
    unsigned* o = outk + ((int64_t)s << 7) + (c4 << 2);
    atomicMax(o + 0, fkey(v.x));
    atomicMax(o + 1, fkey(v.y));
    atomicMax(o + 2, fkey(v.z));
    atomicMax(o + 3, fkey(v.w));
  }
}
__global__ __launch_bounds__(256) void decode_k(unsigned* __restrict__ io, int64_t n4) {
  const int64_t stride = (int64_t)gridDim.x * blockDim.x;
  for (int64_t t = (int64_t)blockIdx.x * blockDim.x + threadIdx.x; t < n4;
       t += stride) {
    uint4* p = ((uint4*)io) + t;
    uint4 k = *p;
    float4 f;
    f.x = k.x ? fdec(k.x) : 0.0f;
    f.y = k.y ? fdec(k.y) : 0.0f;
    f.z = k.z ? fdec(k.z) : 0.0f;
    f.w = k.w ? fdec(k.w) : 0.0f;
    *(float4*)p = f;
  }
}

// ---------------- CSR path ----------------

__global__ __launch_bounds__(256) void zero_u32(unsigned* __restrict__ p, int m) {
  const int stride = gridDim.x * blockDim.x;
  for (int i = blockIdx.x * blockDim.x + threadIdx.x; i < m; i += stride)
    p[i] = 0u;
}

// Pass A: histogram of seg = vt_map[vt_replace[i]].
__global__ __launch_bounds__(256) void seg_hist(
    const int* __restrict__ vt_replace, const int* __restrict__ vt_map,
    unsigned* __restrict__ counts, int n) {
  const int stride = gridDim.x * blockDim.x;
  for (int i = blockIdx.x * blockDim.x + threadIdx.x; i < n; i += stride) {
    const int s = vt_map[vt_replace[i]];
    atomicAdd(&counts[s], 1u);
  }
}

// Pass B: allocate disjoint CSR ranges (segment order irrelevant for max).
// Wave-scan + one atomicAdd(total) per wave replaces a 3-kernel prefix scan.
__global__ __launch_bounds__(256) void alloc_offsets(
    const unsigned* __restrict__ counts, unsigned* __restrict__ cursor,
    unsigned* __restrict__ total, int m) {
  const int i = blockIdx.x * blockDim.x + threadIdx.x;
  const int lane = threadIdx.x & 63;
  const unsigned c = (i < m) ? counts[i] : 0u;
  unsigned x = c;                       // inclusive wave scan
  for (int d = 1; d < 64; d <<= 1) {
    const unsigned t = __shfl_up(x, d, 64);
    if (lane >= d) x += t;
  }
  const unsigned excl = x - c;
  const unsigned tot  = __shfl(x, 63, 64);
  unsigned base = 0;
  if (lane == 63) base = atomicAdd(total, tot);
  base = __shfl(base, 63, 64);
  if (i < m) cursor[i] = base + excl;
}

// Pass C: scatter row ids into CSR buckets (cursor -> end offsets after).
__global__ __launch_bounds__(256) void scatter_rows(
    const int* __restrict__ vt_replace, const int* __restrict__ vt_map,
    unsigned* __restrict__ cursor, int* __restrict__ rowids, int n) {
  const int stride = gridDim.x * blockDim.x;
  for (int i = blockIdx.x * blockDim.x + threadIdx.x; i < n; i += stride) {
    const int s = vt_map[vt_replace[i]];
    const unsigned p = atomicAdd(&cursor[s], 1u);
    rowids[p] = i;
  }
}

// Pass D: one 32-lane group per segment; lane owns 4 channels (floatx4).
// Clamped unroll-4: every batch issues exactly 4 row loads (indices clamped
// to nn-1; redundant loads repeat the last row -> fmax-idempotent, L2-hit).
// No dependent serial tail; 4 x 512B always in flight per group.
__device__ __forceinline__ floatx4 fmax4(floatx4 a, floatx4 b) {
  floatx4 r;
  r.x = fmaxf(a.x, b.x);
  r.y = fmaxf(a.y, b.y);
  r.z = fmaxf(a.z, b.z);
  r.w = fmaxf(a.w, b.w);
  return r;
}

__global__ __launch_bounds__(256) void gather_max4(
    const floatx4* __restrict__ in4, const int* __restrict__ rowids,
    const unsigned* __restrict__ cursor_end, const unsigned* __restrict__ counts,
    floatx4* __restrict__ out4, int m) {
  const int s = blockIdx.x * 8 + (threadIdx.x >> 5);   // 8 groups/block
  if (s >= m) return;
  const int q = threadIdx.x & 31;                      // floatx4 slot in row
  const unsigned end = cursor_end[s];
  const unsigned cnt = counts[s];
  const unsigned start = end - cnt;

  floatx4 acc = (floatx4)(-INFINITY);

  for (unsigned base = start; base < end; base += 32) {
    const int nn = (int)min(32u, end - base);
    int rid = 0;
    if (q < nn) rid = rowids[base + q];      // one coalesced rowid load/group
    const int last = nn - 1;
    for (int j = 0; j < nn; j += 4) {
      const int r0 = __shfl(rid, j, 32);
      const int r1 = __shfl(rid, min(j + 1, last), 32);
      const int r2 = __shfl(rid, min(j + 2, last), 32);
      const int r3 = __shfl(rid, min(j + 3, last), 32);
      const floatx4 v0 = __builtin_nontemporal_load(&in4[(int64_t)r0 * 32 + q]);
      const floatx4 v1 = __builtin_nontemporal_load(&in4[(int64_t)r1 * 32 + q]);
      const floatx4 v2 = __builtin_nontemporal_load(&in4[(int64_t)r2 * 32 + q]);
      const floatx4 v3 = __builtin_nontemporal_load(&in4[(int64_t)r3 * 32 + q]);
      acc = fmax4(acc, fmax4(fmax4(v0, v1), fmax4(v2, v3)));
    }
  }
  if (cnt == 0) acc = (floatx4)(0.0f);       // empty segment -> zeros
  __builtin_nontemporal_store(acc, &out4[(int64_t)s * 32 + q]);
}

// ---------------- launch ----------------
extern "C" void kernel_launch(void* const* d_in, const int* in_sizes, int n_in_args,
                              void* d_out, int out_size, void* d_ws, size_t ws_size,
                              hipStream_t stream) {
  (void)n_in_args;
  const float*  in         = (const float*)d_in[0];
  const int*    vt_replace = (const int*)d_in[1];
  const int*    vt_map     = (const int*)d_in[2];
  const int     n_in = in_sizes[1];
  const int     m    = out_size / C_CH;          // N_OUT

  // workspace carve (256B aligned)
  uintptr_t p = (uintptr_t)d_ws;
  auto carve = [&](size_t bytes) {
    uintptr_t r = p;
    p += (bytes + 255) & ~(size_t)255;
    return (void*)r;
  };
  int*      rowids = (int*)carve((size_t)n_in * 4);
  unsigned* counts = (unsigned*)carve(((size_t)m + 1) * 4);  // counts[m] = total
  unsigned* cursor = (unsigned*)carve((size_t)m * 4);
  unsigned* total  = counts + m;                             // zeroed with counts
  const size_t needed = p - (uintptr_t)d_ws;

  if (ws_size < needed) {
    unsigned* outk = (unsigned*)d_out;
    (void)hipMemsetAsync(d_out, 0, (size_t)out_size * sizeof(float), stream);
    const int64_t n4 = (int64_t)n_in * (C_CH / 4);
    pool_atomic<<<2048, 256, 0, stream>>>((const float4*)in, vt_replace, vt_map, outk, n4);
    decode_k<<<2048, 256, 0, stream>>>(outk, (int64_t)out_size / 4);
    return;
  }

  // zero counts AND total (adjacent) every call — total must restart at 0
  // each replay (graph replays reuse d_ws, harness does not re-poison).
  zero_u32<<<256, 256, 0, stream>>>(counts, m + 1);

  seg_hist<<<2048, 256, 0, stream>>>(vt_replace, vt_map, counts, n_in);

  alloc_offsets<<<(m + 255) / 256, 256, 0, stream>>>(counts, cursor, total, m);

  scatter_rows<<<2048, 256, 0, stream>>>(vt_replace, vt_map, cursor, rowids, n_in);

  const int gc = (m + 7) / 8;   // 8 groups (segments) per block
  gather_max4<<<gc, 256, 0, stream>>>((const floatx4*)in, rowids, cursor, counts,
                                      (floatx4*)d_out, m);
}